// Round 1
// baseline (447.575 us; speedup 1.0000x reference)
//
#include <hip/hip_runtime.h>
#include <math.h>

#define N_NODES 50000
#define N_EDGES 800000
#define IN_F 256
#define OUT_F 64
#define N_HEADS 8
#define SLOPE 0.2f

typedef __attribute__((ext_vector_type(8))) __bf16 bf16x8;
typedef __attribute__((ext_vector_type(4))) __bf16 bf16x4;
typedef __attribute__((ext_vector_type(4))) float floatx4;
typedef __attribute__((ext_vector_type(4))) float f32x4;
typedef __attribute__((ext_vector_type(2))) int i32x2;

#define HIST_BLOCKS   3125    // 800000/256
#define CAST_W_BLOCKS 512     // 8*256*64/256
#define PREP_BLOCKS   (HIST_BLOCKS + CAST_W_BLOCKS)

// Prep: dst-degree histogram + cast/transpose W->bf16.
// x cast is FUSED into the gemm staging now (xb eliminated).
__global__ __launch_bounds__(256) void prep_kernel(const float* __restrict__ W,
                                                   const int* __restrict__ dst,
                                                   __bf16* __restrict__ Wt,
                                                   int* __restrict__ deg) {
    const int b = blockIdx.x;
    const int t = threadIdx.x;
    if (b < HIST_BLOCKS) {
        int e = b * 256 + t;                  // exact: 800000
        atomicAdd(&deg[dst[e]], 1);
    } else {
        int i = (b - HIST_BLOCKS) * 256 + t;  // exact: 131072 elems
        int n = i & (OUT_F - 1);
        int k = (i >> 6) & (IN_F - 1);
        int h = i >> 14;
        Wt[((size_t)h * OUT_F + n) * IN_F + k] = (__bf16)W[i];
    }
}

// Fused GEMM: one block per 32-node tile. Staging now reads fp32 x directly
// (non-temporal: read-once stream, keep L2 for Wt) and casts to bf16 in LDS.
// A[m=lane&15][k=quad*8+j]; B[k][n=lane&15]; D[row=quad*4+reg][col=lane&15].
#define XPAD 264   // 256 + 8 bf16 pad: 528B row stride -> 2-way banks (free)
__global__ __launch_bounds__(256) void mfma_gemm_kernel(const float* __restrict__ x,
                                                        const __bf16* __restrict__ Wt,
                                                        const float* __restrict__ a,
                                                        __bf16* __restrict__ hb,
                                                        float* __restrict__ a_self,
                                                        float* __restrict__ a_neigh) {
    __shared__ __bf16 xs[32][XPAD];
    const int warp = threadIdx.x >> 6;
    const int tile = blockIdx.x;              // 0..1562
    const int n0 = tile * 32;
    const int lane = threadIdx.x & 63;
    const int l15 = lane & 15;
    const int quad = lane >> 4;
    const int h0 = warp * 2;

    // ---- stage x tile (32 rows x 256 k) with inline fp32->bf16 cast ----
#pragma unroll
    for (int i = 0; i < 8; i++) {
        int c4 = i * 256 + threadIdx.x;       // float4 chunk id 0..2047
        int row = c4 >> 6;                    // 64 chunks per row
        int col = (c4 & 63) * 4;
        int node = n0 + row;
        node = (node < N_NODES) ? node : (N_NODES - 1);
        f32x4 v = __builtin_nontemporal_load((const f32x4*)x + (size_t)node * 64 + (c4 & 63));
        bf16x4 o;
        o[0] = (__bf16)v[0]; o[1] = (__bf16)v[1]; o[2] = (__bf16)v[2]; o[3] = (__bf16)v[3];
        *(bf16x4*)&xs[row][col] = o;
    }
    __syncthreads();

    floatx4 acc[2][2][4];   // [head][rowblock][col]
#pragma unroll
    for (int hh = 0; hh < 2; hh++)
#pragma unroll
        for (int i = 0; i < 2; i++)
#pragma unroll
            for (int c = 0; c < 4; c++) acc[hh][i][c] = floatx4{0.f, 0.f, 0.f, 0.f};

    const __bf16* wb0 = Wt + ((size_t)h0 * OUT_F + l15) * IN_F + quad * 8;
    const __bf16* wb1 = wb0 + (size_t)OUT_F * IN_F;

#pragma unroll
    for (int k0 = 0; k0 < IN_F; k0 += 32) {
        bf16x8 a0 = *(const bf16x8*)&xs[l15][k0 + quad * 8];
        bf16x8 a1 = *(const bf16x8*)&xs[l15 + 16][k0 + quad * 8];
#pragma unroll
        for (int c = 0; c < 4; c++) {
            bf16x8 b0 = *(const bf16x8*)(wb0 + (size_t)c * 16 * IN_F + k0);
            acc[0][0][c] = __builtin_amdgcn_mfma_f32_16x16x32_bf16(a0, b0, acc[0][0][c], 0, 0, 0);
            acc[0][1][c] = __builtin_amdgcn_mfma_f32_16x16x32_bf16(a1, b0, acc[0][1][c], 0, 0, 0);
            bf16x8 b1 = *(const bf16x8*)(wb1 + (size_t)c * 16 * IN_F + k0);
            acc[1][0][c] = __builtin_amdgcn_mfma_f32_16x16x32_bf16(a0, b1, acc[1][0][c], 0, 0, 0);
            acc[1][1][c] = __builtin_amdgcn_mfma_f32_16x16x32_bf16(a1, b1, acc[1][1][c], 0, 0, 0);
        }
    }

    __syncthreads();   // all waves done reading xs; reuse as transpose buffer
    __bf16* my = (__bf16*)xs + warp * (32 * OUT_F);

#pragma unroll
    for (int hh = 0; hh < 2; hh++) {
        const int head = h0 + hh;
        float av0[4], av1[4];
#pragma unroll
        for (int c = 0; c < 4; c++) {
            av0[c] = a[head * 2 * OUT_F + c * 16 + l15];
            av1[c] = a[head * 2 * OUT_F + OUT_F + c * 16 + l15];
        }
#pragma unroll
        for (int i = 0; i < 2; i++) {
#pragma unroll
            for (int reg = 0; reg < 4; reg++) {
                float ps = 0.f, pn = 0.f;
#pragma unroll
                for (int c = 0; c < 4; c++) {
                    float v = acc[hh][i][c][reg];
                    ps = fmaf(v, av0[c], ps);
                    pn = fmaf(v, av1[c], pn);
                    my[(i * 16 + quad * 4 + reg) * OUT_F + c * 16 + l15] = (__bf16)v;
                }
#pragma unroll
                for (int off = 1; off < 16; off <<= 1) {
                    ps += __shfl_xor(ps, off, 64);
                    pn += __shfl_xor(pn, off, 64);
                }
                int node = n0 + i * 16 + quad * 4 + reg;
                if (l15 == 0 && node < N_NODES) {
                    a_self[node * N_HEADS + head] = ps;
                    a_neigh[node * N_HEADS + head] = pn;
                }
            }
        }
        // coalesced bf16 h store (wave-private region, in-wave ordering)
#pragma unroll
        for (int pass = 0; pass < 4; pass++) {
            int row = pass * 8 + (lane >> 3);
            int node = n0 + row;
            bf16x8 v = *(const bf16x8*)&my[row * OUT_F + (lane & 7) * 8];
            if (node < N_NODES)
                *(bf16x8*)(hb + ((size_t)node * N_HEADS + head) * OUT_F + (lane & 7) * 8) = v;
        }
    }
}

#define SB 512
#define NSB 98   // ceil(50000/512)
__global__ void scanA(const int* __restrict__ deg, int* __restrict__ start,
                      int* __restrict__ bsum) {
    __shared__ int tmp[SB];
    int t = threadIdx.x, i = blockIdx.x * SB + t;
    int v = (i < N_NODES) ? deg[i] : 0;
    tmp[t] = v;
    for (int off = 1; off < SB; off <<= 1) {
        __syncthreads();
        int add = (t >= off) ? tmp[t - off] : 0;
        __syncthreads();
        tmp[t] += add;
    }
    if (i < N_NODES) start[i] = tmp[t] - v;
    if (t == SB - 1) bsum[blockIdx.x] = tmp[SB - 1];
}

__global__ void scanC(int* __restrict__ start, const int* __restrict__ bsum,
                      int* __restrict__ cursor) {
    __shared__ int pre[128];
    int t = threadIdx.x;
    if (t < 128) pre[t] = (t < NSB) ? bsum[t] : 0;
    __syncthreads();
    for (int off = 1; off < 128; off <<= 1) {
        int add = (t < 128 && t >= off) ? pre[t - off] : 0;
        __syncthreads();
        if (t < 128) pre[t] += add;
        __syncthreads();
    }
    int excl = (blockIdx.x == 0) ? 0 : pre[blockIdx.x - 1];
    int i = blockIdx.x * SB + t;
    if (i < N_NODES) {
        int s = start[i] + excl;
        start[i] = s;
        cursor[i] = s;
    }
}

// pack {src, m-bits} into one 8B entry. Non-temporal scatter: 8B goes straight
// to memory (HBM byte-enables) instead of cross-XCD dirty-line ping-pong.
__global__ void fill_kernel(const int* __restrict__ src, const int* __restrict__ dst,
                            const float* __restrict__ M, int* __restrict__ cursor,
                            i32x2* __restrict__ csr_sm) {
    int e = blockIdx.x * 256 + threadIdx.x;
    if (e < N_EDGES) {
        int d = dst[e];
        int pos = atomicAdd(&cursor[d], 1);
        i32x2 v;
        v.x = src[e];
        v.y = __float_as_int(M[e]);
        __builtin_nontemporal_store(v, csr_sm + pos);
    }
}

// One wave per node, ALL 8 heads per iteration. Lane l: head = l>>3,
// features (l&7)*8..+8. 2-deep index pipeline: csr entry prefetched 2 edges
// ahead (NT: read-once stream), gathers issued 1 ahead from an index that is
// already resident -> no intra-iteration csr->gather waitcnt. out stores are
// non-temporal so the 100MB write stream doesn't evict the hb gather set
// from L2.
__global__ __launch_bounds__(256) void agg_kernel(const __bf16* __restrict__ hb,
                                                  const float* __restrict__ a_self,
                                                  const float* __restrict__ a_neigh,
                                                  const int* __restrict__ start,
                                                  const int* __restrict__ deg,
                                                  const i32x2* __restrict__ csr_sm,
                                                  float* __restrict__ out) {
    int n = blockIdx.x * 4 + (threadIdx.x >> 6);
    if (n >= N_NODES) return;
    const int lane = threadIdx.x & 63;
    const int head = lane >> 3;

    const int s0 = start[n];
    const int d = deg[n];
    const float an = a_neigh[(n << 3) + head];
    const __bf16* hbl = hb + (lane << 3);
    const float* asl = a_self + head;

    float facc[8];
#pragma unroll
    for (int k = 0; k < 8; k++) facc[k] = 0.f;
    float den = 0.f;

    i32x2 zero = 0;
    i32x2 sm0 = (d > 0) ? __builtin_nontemporal_load(csr_sm + s0) : zero;
    i32x2 sm1 = (d > 1) ? __builtin_nontemporal_load(csr_sm + s0 + 1) : sm0;
    float as0 = asl[sm0.x << 3];
    bf16x8 hv0 = *(const bf16x8*)(hbl + (sm0.x << 9));

    for (int j = 0; j < d; j++) {
        // index 2 ahead (independent), gathers 1 ahead (index already resident)
        i32x2 sm2 = (j + 2 < d) ? __builtin_nontemporal_load(csr_sm + s0 + j + 2) : sm1;
        float as1 = asl[sm1.x << 3];
        bf16x8 hv1 = *(const bf16x8*)(hbl + (sm1.x << 9));

        float e = as0 + an;
        e = (e > 0.f) ? e : SLOPE * e;
        const float w = __expf(e * __int_as_float(sm0.y));
#pragma unroll
        for (int k = 0; k < 8; k++) facc[k] = fmaf(w, (float)hv0[k], facc[k]);
        den += w;

        sm0 = sm1; as0 = as1; hv0 = hv1;
        sm1 = sm2;
    }

    const float inv = 1.f / (den + 1e-16f);
    float r[8];
#pragma unroll
    for (int k = 0; k < 8; k++) {
        float v = facc[k] * inv;
        r[k] = (v > 0.f) ? v : expm1f(v);   // elu
    }
    float* ob = &out[((size_t)n << 9) + (lane << 3)];
    f32x4 lo = {r[0], r[1], r[2], r[3]};
    f32x4 hi = {r[4], r[5], r[6], r[7]};
    __builtin_nontemporal_store(lo, (f32x4*)ob);
    __builtin_nontemporal_store(hi, (f32x4*)(ob + 4));
}

extern "C" void kernel_launch(void* const* d_in, const int* in_sizes, int n_in,
                              void* d_out, int out_size, void* d_ws, size_t ws_size,
                              hipStream_t stream) {
    const float* x   = (const float*)d_in[0];
    const int*   src = (const int*)d_in[1];
    const int*   dst = (const int*)d_in[2];
    const float* M   = (const float*)d_in[3];
    const float* W   = (const float*)d_in[4];
    const float* a   = (const float*)d_in[5];
    float* out = (float*)d_out;

    char* p = (char*)d_ws;
    auto alloc = [&](size_t bytes) {
        char* r = p;
        p += (bytes + 255) & ~(size_t)255;
        return r;
    };
    __bf16* hb      = (__bf16*)alloc(sizeof(__bf16) * (size_t)N_NODES * N_HEADS * OUT_F);
    float*  a_self  = (float*)alloc(sizeof(float) * N_NODES * N_HEADS);
    float*  a_neigh = (float*)alloc(sizeof(float) * N_NODES * N_HEADS);
    int*    deg     = (int*)alloc(sizeof(int) * N_NODES);
    int*    start   = (int*)alloc(sizeof(int) * N_NODES);
    int*    cursor  = (int*)alloc(sizeof(int) * N_NODES);
    int*    bsum    = (int*)alloc(sizeof(int) * 256);
    i32x2*  csr_sm  = (i32x2*)alloc(sizeof(i32x2) * N_EDGES);
    __bf16* Wt      = (__bf16*)alloc(sizeof(__bf16) * N_HEADS * IN_F * OUT_F);

    // --- prep: zero deg, then fused hist + cast_w ---
    hipMemsetAsync(deg, 0, sizeof(int) * N_NODES, stream);
    prep_kernel<<<PREP_BLOCKS, 256, 0, stream>>>(W, dst, Wt, deg);

    // --- CSR scan + fill ---
    scanA<<<NSB, SB, 0, stream>>>(deg, start, bsum);
    scanC<<<NSB, SB, 0, stream>>>(start, bsum, cursor);
    fill_kernel<<<(N_EDGES + 255) / 256, 256, 0, stream>>>(src, dst, M, cursor, csr_sm);

    // --- fused cast + feature transform + attention dots (bf16 MFMA) ---
    mfma_gemm_kernel<<<1563, 256, 0, stream>>>(x, Wt, a, hb, a_self, a_neigh);

    // --- fused attention + aggregation + elu (all heads per wave) ---
    agg_kernel<<<(N_NODES + 3) / 4, 256, 0, stream>>>(hb, a_self, a_neigh,
                                                      start, deg, csr_sm, out);
}

// Round 2
// 436.762 us; speedup vs baseline: 1.0248x; 1.0248x over previous
//
#include <hip/hip_runtime.h>
#include <math.h>

#define N_NODES 50000
#define N_EDGES 800000
#define IN_F 256
#define OUT_F 64
#define N_HEADS 8
#define SLOPE 0.2f

typedef __attribute__((ext_vector_type(8))) __bf16 bf16x8;
typedef __attribute__((ext_vector_type(4))) __bf16 bf16x4;
typedef __attribute__((ext_vector_type(4))) float floatx4;
typedef __attribute__((ext_vector_type(4))) float f32x4;
typedef __attribute__((ext_vector_type(2))) int i32x2;

#define HIST_BLOCKS   3125    // 800000/256
#define CAST_W_BLOCKS 512     // 8*256*64/256
#define PREP_BLOCKS   (HIST_BLOCKS + CAST_W_BLOCKS)

// Prep: dst-degree histogram + cast/transpose W->bf16.
// x cast is FUSED into the gemm staging (xb eliminated).
__global__ __launch_bounds__(256) void prep_kernel(const float* __restrict__ W,
                                                   const int* __restrict__ dst,
                                                   __bf16* __restrict__ Wt,
                                                   int* __restrict__ deg) {
    const int b = blockIdx.x;
    const int t = threadIdx.x;
    if (b < HIST_BLOCKS) {
        int e = b * 256 + t;                  // exact: 800000
        atomicAdd(&deg[dst[e]], 1);
    } else {
        int i = (b - HIST_BLOCKS) * 256 + t;  // exact: 131072 elems
        int n = i & (OUT_F - 1);
        int k = (i >> 6) & (IN_F - 1);
        int h = i >> 14;
        Wt[((size_t)h * OUT_F + n) * IN_F + k] = (__bf16)W[i];
    }
}

// Fused GEMM: one block per 32-node tile. Staging reads fp32 x directly
// (non-temporal: read-once stream, keep L2 for Wt) and casts to bf16 in LDS.
// A[m=lane&15][k=quad*8+j]; B[k][n=lane&15]; D[row=quad*4+reg][col=lane&15].
#define XPAD 264   // 256 + 8 bf16 pad: 528B row stride -> 2-way banks (free)
__global__ __launch_bounds__(256) void mfma_gemm_kernel(const float* __restrict__ x,
                                                        const __bf16* __restrict__ Wt,
                                                        const float* __restrict__ a,
                                                        __bf16* __restrict__ hb,
                                                        float* __restrict__ a_self,
                                                        float* __restrict__ a_neigh) {
    __shared__ __bf16 xs[32][XPAD];
    const int warp = threadIdx.x >> 6;
    const int tile = blockIdx.x;              // 0..1562
    const int n0 = tile * 32;
    const int lane = threadIdx.x & 63;
    const int l15 = lane & 15;
    const int quad = lane >> 4;
    const int h0 = warp * 2;

    // ---- stage x tile (32 rows x 256 k) with inline fp32->bf16 cast ----
#pragma unroll
    for (int i = 0; i < 8; i++) {
        int c4 = i * 256 + threadIdx.x;       // float4 chunk id 0..2047
        int row = c4 >> 6;                    // 64 chunks per row
        int col = (c4 & 63) * 4;
        int node = n0 + row;
        node = (node < N_NODES) ? node : (N_NODES - 1);
        f32x4 v = __builtin_nontemporal_load((const f32x4*)x + (size_t)node * 64 + (c4 & 63));
        bf16x4 o;
        o[0] = (__bf16)v[0]; o[1] = (__bf16)v[1]; o[2] = (__bf16)v[2]; o[3] = (__bf16)v[3];
        *(bf16x4*)&xs[row][col] = o;
    }
    __syncthreads();

    floatx4 acc[2][2][4];   // [head][rowblock][col]
#pragma unroll
    for (int hh = 0; hh < 2; hh++)
#pragma unroll
        for (int i = 0; i < 2; i++)
#pragma unroll
            for (int c = 0; c < 4; c++) acc[hh][i][c] = floatx4{0.f, 0.f, 0.f, 0.f};

    const __bf16* wb0 = Wt + ((size_t)h0 * OUT_F + l15) * IN_F + quad * 8;
    const __bf16* wb1 = wb0 + (size_t)OUT_F * IN_F;

#pragma unroll
    for (int k0 = 0; k0 < IN_F; k0 += 32) {
        bf16x8 a0 = *(const bf16x8*)&xs[l15][k0 + quad * 8];
        bf16x8 a1 = *(const bf16x8*)&xs[l15 + 16][k0 + quad * 8];
#pragma unroll
        for (int c = 0; c < 4; c++) {
            bf16x8 b0 = *(const bf16x8*)(wb0 + (size_t)c * 16 * IN_F + k0);
            acc[0][0][c] = __builtin_amdgcn_mfma_f32_16x16x32_bf16(a0, b0, acc[0][0][c], 0, 0, 0);
            acc[0][1][c] = __builtin_amdgcn_mfma_f32_16x16x32_bf16(a1, b0, acc[0][1][c], 0, 0, 0);
            bf16x8 b1 = *(const bf16x8*)(wb1 + (size_t)c * 16 * IN_F + k0);
            acc[1][0][c] = __builtin_amdgcn_mfma_f32_16x16x32_bf16(a0, b1, acc[1][0][c], 0, 0, 0);
            acc[1][1][c] = __builtin_amdgcn_mfma_f32_16x16x32_bf16(a1, b1, acc[1][1][c], 0, 0, 0);
        }
    }

    __syncthreads();   // all waves done reading xs; reuse as transpose buffer
    __bf16* my = (__bf16*)xs + warp * (32 * OUT_F);

#pragma unroll
    for (int hh = 0; hh < 2; hh++) {
        const int head = h0 + hh;
        float av0[4], av1[4];
#pragma unroll
        for (int c = 0; c < 4; c++) {
            av0[c] = a[head * 2 * OUT_F + c * 16 + l15];
            av1[c] = a[head * 2 * OUT_F + OUT_F + c * 16 + l15];
        }
#pragma unroll
        for (int i = 0; i < 2; i++) {
#pragma unroll
            for (int reg = 0; reg < 4; reg++) {
                float ps = 0.f, pn = 0.f;
#pragma unroll
                for (int c = 0; c < 4; c++) {
                    float v = acc[hh][i][c][reg];
                    ps = fmaf(v, av0[c], ps);
                    pn = fmaf(v, av1[c], pn);
                    my[(i * 16 + quad * 4 + reg) * OUT_F + c * 16 + l15] = (__bf16)v;
                }
#pragma unroll
                for (int off = 1; off < 16; off <<= 1) {
                    ps += __shfl_xor(ps, off, 64);
                    pn += __shfl_xor(pn, off, 64);
                }
                int node = n0 + i * 16 + quad * 4 + reg;
                if (l15 == 0 && node < N_NODES) {
                    a_self[node * N_HEADS + head] = ps;
                    a_neigh[node * N_HEADS + head] = pn;
                }
            }
        }
        // coalesced bf16 h store (wave-private region, in-wave ordering)
#pragma unroll
        for (int pass = 0; pass < 4; pass++) {
            int row = pass * 8 + (lane >> 3);
            int node = n0 + row;
            bf16x8 v = *(const bf16x8*)&my[row * OUT_F + (lane & 7) * 8];
            if (node < N_NODES)
                *(bf16x8*)(hb + ((size_t)node * N_HEADS + head) * OUT_F + (lane & 7) * 8) = v;
        }
    }
}

#define SB 512
#define NSB 98   // ceil(50000/512)
__global__ void scanA(const int* __restrict__ deg, int* __restrict__ start,
                      int* __restrict__ bsum) {
    __shared__ int tmp[SB];
    int t = threadIdx.x, i = blockIdx.x * SB + t;
    int v = (i < N_NODES) ? deg[i] : 0;
    tmp[t] = v;
    for (int off = 1; off < SB; off <<= 1) {
        __syncthreads();
        int add = (t >= off) ? tmp[t - off] : 0;
        __syncthreads();
        tmp[t] += add;
    }
    if (i < N_NODES) start[i] = tmp[t] - v;
    if (t == SB - 1) bsum[blockIdx.x] = tmp[SB - 1];
}

__global__ void scanC(int* __restrict__ start, const int* __restrict__ bsum,
                      int* __restrict__ cursor) {
    __shared__ int pre[128];
    int t = threadIdx.x;
    if (t < 128) pre[t] = (t < NSB) ? bsum[t] : 0;
    __syncthreads();
    for (int off = 1; off < 128; off <<= 1) {
        int add = (t < 128 && t >= off) ? pre[t - off] : 0;
        __syncthreads();
        if (t < 128) pre[t] += add;
        __syncthreads();
    }
    int excl = (blockIdx.x == 0) ? 0 : pre[blockIdx.x - 1];
    int i = blockIdx.x * SB + t;
    if (i < N_NODES) {
        int s = start[i] + excl;
        start[i] = s;
        cursor[i] = s;
    }
}

// pack {src, m-bits} into one 8B entry. NT scatter: 8B goes straight to
// memory instead of cross-XCD dirty-line ping-pong.
__global__ void fill_kernel(const int* __restrict__ src, const int* __restrict__ dst,
                            const float* __restrict__ M, int* __restrict__ cursor,
                            i32x2* __restrict__ csr_sm) {
    int e = blockIdx.x * 256 + threadIdx.x;
    if (e < N_EDGES) {
        int d = dst[e];
        int pos = atomicAdd(&cursor[d], 1);
        i32x2 v;
        v.x = src[e];
        v.y = __float_as_int(M[e]);
        __builtin_nontemporal_store(v, csr_sm + pos);
    }
}

// One wave per node, ALL 8 heads per iteration. Lane l: head = l>>3,
// features (l&7)*8..+8. Depth-2 gather pipeline: unroll-by-2, named
// registers only (runtime-indexed arrays spill to scratch). csr entries
// prefetched 4 ahead (plain loads: 8 entries/line reused sequentially),
// h-row + a_self gathers issued 2 edges ahead so each gather has two full
// iterations of compute+issue to land. Plain out stores (NT regressed R1).
__global__ __launch_bounds__(256) void agg_kernel(const __bf16* __restrict__ hb,
                                                  const float* __restrict__ a_self,
                                                  const float* __restrict__ a_neigh,
                                                  const int* __restrict__ start,
                                                  const int* __restrict__ deg,
                                                  const i32x2* __restrict__ csr_sm,
                                                  float* __restrict__ out) {
    int n = blockIdx.x * 4 + (threadIdx.x >> 6);
    if (n >= N_NODES) return;
    const int lane = threadIdx.x & 63;
    const int head = lane >> 3;

    const int d = deg[n];
    const float an = a_neigh[(n << 3) + head];
    const __bf16* hbl = hb + (lane << 3);
    const float* asl = a_self + head;
    const i32x2* cp = csr_sm + start[n];

    float facc[8];
#pragma unroll
    for (int k = 0; k < 8; k++) facc[k] = 0.f;
    float den = 0.f;

    i32x2 zero = 0;
    i32x2 smA = (d > 0) ? cp[0] : zero;
    i32x2 smB = (d > 1) ? cp[1] : smA;
    i32x2 smC = (d > 2) ? cp[2] : smB;
    i32x2 smD = (d > 3) ? cp[3] : smC;
    float  asA = asl[smA.x << 3];
    bf16x8 hvA = *(const bf16x8*)(hbl + ((size_t)smA.x << 9));
    float  asB = asl[smB.x << 3];
    bf16x8 hvB = *(const bf16x8*)(hbl + ((size_t)smB.x << 9));

    int j = 0;
    for (; j + 2 <= d; j += 2) {
        // issue: csr 4 ahead, gathers 2 ahead
        i32x2 smE = (j + 4 < d) ? cp[j + 4] : smD;
        i32x2 smF = (j + 5 < d) ? cp[j + 5] : smE;
        float  asC = asl[smC.x << 3];
        bf16x8 hvC = *(const bf16x8*)(hbl + ((size_t)smC.x << 9));
        float  asD = asl[smD.x << 3];
        bf16x8 hvD = *(const bf16x8*)(hbl + ((size_t)smD.x << 9));

        // compute edge j (slot A)
        float eA = asA + an;
        eA = (eA > 0.f) ? eA : SLOPE * eA;
        const float wA = __expf(eA * __int_as_float(smA.y));
#pragma unroll
        for (int k = 0; k < 8; k++) facc[k] = fmaf(wA, (float)hvA[k], facc[k]);
        den += wA;

        // compute edge j+1 (slot B)
        float eB = asB + an;
        eB = (eB > 0.f) ? eB : SLOPE * eB;
        const float wB = __expf(eB * __int_as_float(smB.y));
#pragma unroll
        for (int k = 0; k < 8; k++) facc[k] = fmaf(wB, (float)hvB[k], facc[k]);
        den += wB;

        // rotate pipeline
        smA = smC; asA = asC; hvA = hvC;
        smB = smD; asB = asD; hvB = hvD;
        smC = smE; smD = smF;
    }
    if (j < d) {   // odd tail: one edge left in slot A
        float eA = asA + an;
        eA = (eA > 0.f) ? eA : SLOPE * eA;
        const float wA = __expf(eA * __int_as_float(smA.y));
#pragma unroll
        for (int k = 0; k < 8; k++) facc[k] = fmaf(wA, (float)hvA[k], facc[k]);
        den += wA;
    }

    const float inv = 1.f / (den + 1e-16f);
    float r[8];
#pragma unroll
    for (int k = 0; k < 8; k++) {
        float v = facc[k] * inv;
        r[k] = (v > 0.f) ? v : expm1f(v);   // elu
    }
    float* ob = &out[((size_t)n << 9) + (lane << 3)];
    *(float4*)(ob)     = make_float4(r[0], r[1], r[2], r[3]);
    *(float4*)(ob + 4) = make_float4(r[4], r[5], r[6], r[7]);
}

extern "C" void kernel_launch(void* const* d_in, const int* in_sizes, int n_in,
                              void* d_out, int out_size, void* d_ws, size_t ws_size,
                              hipStream_t stream) {
    const float* x   = (const float*)d_in[0];
    const int*   src = (const int*)d_in[1];
    const int*   dst = (const int*)d_in[2];
    const float* M   = (const float*)d_in[3];
    const float* W   = (const float*)d_in[4];
    const float* a   = (const float*)d_in[5];
    float* out = (float*)d_out;

    char* p = (char*)d_ws;
    auto alloc = [&](size_t bytes) {
        char* r = p;
        p += (bytes + 255) & ~(size_t)255;
        return r;
    };
    __bf16* hb      = (__bf16*)alloc(sizeof(__bf16) * (size_t)N_NODES * N_HEADS * OUT_F);
    float*  a_self  = (float*)alloc(sizeof(float) * N_NODES * N_HEADS);
    float*  a_neigh = (float*)alloc(sizeof(float) * N_NODES * N_HEADS);
    int*    deg     = (int*)alloc(sizeof(int) * N_NODES);
    int*    start   = (int*)alloc(sizeof(int) * N_NODES);
    int*    cursor  = (int*)alloc(sizeof(int) * N_NODES);
    int*    bsum    = (int*)alloc(sizeof(int) * 256);
    i32x2*  csr_sm  = (i32x2*)alloc(sizeof(i32x2) * N_EDGES);
    __bf16* Wt      = (__bf16*)alloc(sizeof(__bf16) * N_HEADS * IN_F * OUT_F);

    // --- prep: zero deg, then fused hist + cast_w ---
    hipMemsetAsync(deg, 0, sizeof(int) * N_NODES, stream);
    prep_kernel<<<PREP_BLOCKS, 256, 0, stream>>>(W, dst, Wt, deg);

    // --- CSR scan + fill ---
    scanA<<<NSB, SB, 0, stream>>>(deg, start, bsum);
    scanC<<<NSB, SB, 0, stream>>>(start, bsum, cursor);
    fill_kernel<<<(N_EDGES + 255) / 256, 256, 0, stream>>>(src, dst, M, cursor, csr_sm);

    // --- fused cast + feature transform + attention dots (bf16 MFMA) ---
    mfma_gemm_kernel<<<1563, 256, 0, stream>>>(x, Wt, a, hb, a_self, a_neigh);

    // --- fused attention + aggregation + elu (all heads per wave) ---
    agg_kernel<<<(N_NODES + 3) / 4, 256, 0, stream>>>(hb, a_self, a_neigh,
                                                      start, deg, csr_sm, out);
}

// Round 3
// 404.639 us; speedup vs baseline: 1.1061x; 1.0794x over previous
//
#include <hip/hip_runtime.h>
#include <math.h>

#define N_NODES 50000
#define N_EDGES 800000
#define IN_F 256
#define OUT_F 64
#define N_HEADS 8
#define SLOPE 0.2f

typedef __attribute__((ext_vector_type(8))) __bf16 bf16x8;
typedef __attribute__((ext_vector_type(4))) __bf16 bf16x4;
typedef __attribute__((ext_vector_type(4))) float floatx4;
typedef __attribute__((ext_vector_type(4))) float f32x4;
typedef __attribute__((ext_vector_type(2))) int i32x2;
typedef __attribute__((ext_vector_type(8))) char schar8;

#define HIST_BLOCKS   3125    // 800000/256
#define CAST_W_BLOCKS 512     // 8*256*64/256
#define PREP_BLOCKS   (HIST_BLOCKS + CAST_W_BLOCKS)

// Prep: dst-degree histogram + cast/transpose W->bf16.
__global__ __launch_bounds__(256) void prep_kernel(const float* __restrict__ W,
                                                   const int* __restrict__ dst,
                                                   __bf16* __restrict__ Wt,
                                                   int* __restrict__ deg) {
    const int b = blockIdx.x;
    const int t = threadIdx.x;
    if (b < HIST_BLOCKS) {
        int e = b * 256 + t;                  // exact: 800000
        atomicAdd(&deg[dst[e]], 1);
    } else {
        int i = (b - HIST_BLOCKS) * 256 + t;  // exact: 131072 elems
        int n = i & (OUT_F - 1);
        int k = (i >> 6) & (IN_F - 1);
        int h = i >> 14;
        Wt[((size_t)h * OUT_F + n) * IN_F + k] = (__bf16)W[i];
    }
}

// Fused GEMM + attention dots + int8 quantization of h.
// h is stored int8 with a per-(node,head) symmetric scale (rowmax/127).
// Attention dots (a_self/a_neigh) stay fp32 from the MFMA accumulator, so
// attention weights are unaffected by quantization. Error bound on output:
// convex combination of per-element quant error <= rowmax/254 (~0.035 worst).
#define XPAD 264   // 256 + 8 bf16 pad: 528B row stride -> 2-way banks (free)
__global__ __launch_bounds__(256) void mfma_gemm_kernel(const float* __restrict__ x,
                                                        const __bf16* __restrict__ Wt,
                                                        const float* __restrict__ a,
                                                        signed char* __restrict__ hb,
                                                        float2* __restrict__ asc,
                                                        float* __restrict__ a_neigh) {
    __shared__ __bf16 xs[32][XPAD];
    const int warp = threadIdx.x >> 6;
    const int tile = blockIdx.x;              // 0..1562
    const int n0 = tile * 32;
    const int lane = threadIdx.x & 63;
    const int l15 = lane & 15;
    const int quad = lane >> 4;
    const int h0 = warp * 2;

    // ---- stage x tile (32 rows x 256 k) with inline fp32->bf16 cast ----
#pragma unroll
    for (int i = 0; i < 8; i++) {
        int c4 = i * 256 + threadIdx.x;       // float4 chunk id 0..2047
        int row = c4 >> 6;                    // 64 chunks per row
        int col = (c4 & 63) * 4;
        int node = n0 + row;
        node = (node < N_NODES) ? node : (N_NODES - 1);
        f32x4 v = __builtin_nontemporal_load((const f32x4*)x + (size_t)node * 64 + (c4 & 63));
        bf16x4 o;
        o[0] = (__bf16)v[0]; o[1] = (__bf16)v[1]; o[2] = (__bf16)v[2]; o[3] = (__bf16)v[3];
        *(bf16x4*)&xs[row][col] = o;
    }
    __syncthreads();

    floatx4 acc[2][2][4];   // [head][rowblock][col]
#pragma unroll
    for (int hh = 0; hh < 2; hh++)
#pragma unroll
        for (int i = 0; i < 2; i++)
#pragma unroll
            for (int c = 0; c < 4; c++) acc[hh][i][c] = floatx4{0.f, 0.f, 0.f, 0.f};

    const __bf16* wb0 = Wt + ((size_t)h0 * OUT_F + l15) * IN_F + quad * 8;
    const __bf16* wb1 = wb0 + (size_t)OUT_F * IN_F;

#pragma unroll
    for (int k0 = 0; k0 < IN_F; k0 += 32) {
        bf16x8 a0 = *(const bf16x8*)&xs[l15][k0 + quad * 8];
        bf16x8 a1 = *(const bf16x8*)&xs[l15 + 16][k0 + quad * 8];
#pragma unroll
        for (int c = 0; c < 4; c++) {
            bf16x8 b0 = *(const bf16x8*)(wb0 + (size_t)c * 16 * IN_F + k0);
            acc[0][0][c] = __builtin_amdgcn_mfma_f32_16x16x32_bf16(a0, b0, acc[0][0][c], 0, 0, 0);
            acc[0][1][c] = __builtin_amdgcn_mfma_f32_16x16x32_bf16(a1, b0, acc[0][1][c], 0, 0, 0);
            bf16x8 b1 = *(const bf16x8*)(wb1 + (size_t)c * 16 * IN_F + k0);
            acc[1][0][c] = __builtin_amdgcn_mfma_f32_16x16x32_bf16(a0, b1, acc[1][0][c], 0, 0, 0);
            acc[1][1][c] = __builtin_amdgcn_mfma_f32_16x16x32_bf16(a1, b1, acc[1][1][c], 0, 0, 0);
        }
    }

    __syncthreads();   // all waves done reading xs; reuse as int8 transpose buf
    char* myc = (char*)xs + warp * (32 * OUT_F);   // 2KB per warp, disjoint

#pragma unroll
    for (int hh = 0; hh < 2; hh++) {
        const int head = h0 + hh;
        float av0[4], av1[4];
#pragma unroll
        for (int c = 0; c < 4; c++) {
            av0[c] = a[head * 2 * OUT_F + c * 16 + l15];
            av1[c] = a[head * 2 * OUT_F + OUT_F + c * 16 + l15];
        }
#pragma unroll
        for (int i = 0; i < 2; i++) {
#pragma unroll
            for (int reg = 0; reg < 4; reg++) {
                float ps = 0.f, pn = 0.f, rm = 0.f;
#pragma unroll
                for (int c = 0; c < 4; c++) {
                    float v = acc[hh][i][c][reg];
                    ps = fmaf(v, av0[c], ps);
                    pn = fmaf(v, av1[c], pn);
                    rm = fmaxf(rm, fabsf(v));
                }
#pragma unroll
                for (int off = 1; off < 16; off <<= 1) {
                    ps += __shfl_xor(ps, off, 64);
                    pn += __shfl_xor(pn, off, 64);
                    rm = fmaxf(rm, __shfl_xor(rm, off, 64));
                }
                const float inv = (rm > 0.f) ? 127.f / rm : 0.f;
                const int rowoff = (i * 16 + quad * 4 + reg) * OUT_F;
#pragma unroll
                for (int c = 0; c < 4; c++) {
                    float q = rintf(acc[hh][i][c][reg] * inv);
                    q = fminf(fmaxf(q, -127.f), 127.f);
                    myc[rowoff + c * 16 + l15] = (char)(int)q;
                }
                int node = n0 + i * 16 + quad * 4 + reg;
                if (l15 == 0 && node < N_NODES) {
                    asc[node * N_HEADS + head] = make_float2(ps, rm * (1.f / 127.f));
                    a_neigh[node * N_HEADS + head] = pn;
                }
            }
        }
        // coalesced int8 h store (wave-private region, in-wave LDS ordering)
#pragma unroll
        for (int pass = 0; pass < 4; pass++) {
            int row = pass * 8 + (lane >> 3);
            int node = n0 + row;
            schar8 v = *(const schar8*)&myc[row * OUT_F + (lane & 7) * 8];
            if (node < N_NODES)
                *(schar8*)(hb + ((size_t)(node * N_HEADS + head) << 6) + (lane & 7) * 8) = v;
        }
    }
}

#define SB 512
#define NSB 98   // ceil(50000/512)
__global__ void scanA(const int* __restrict__ deg, int* __restrict__ start,
                      int* __restrict__ bsum) {
    __shared__ int tmp[SB];
    int t = threadIdx.x, i = blockIdx.x * SB + t;
    int v = (i < N_NODES) ? deg[i] : 0;
    tmp[t] = v;
    for (int off = 1; off < SB; off <<= 1) {
        __syncthreads();
        int add = (t >= off) ? tmp[t - off] : 0;
        __syncthreads();
        tmp[t] += add;
    }
    if (i < N_NODES) start[i] = tmp[t] - v;
    if (t == SB - 1) bsum[blockIdx.x] = tmp[SB - 1];
}

__global__ void scanC(int* __restrict__ start, const int* __restrict__ bsum,
                      int* __restrict__ cursor) {
    __shared__ int pre[128];
    int t = threadIdx.x;
    if (t < 128) pre[t] = (t < NSB) ? bsum[t] : 0;
    __syncthreads();
    for (int off = 1; off < 128; off <<= 1) {
        int add = (t < 128 && t >= off) ? pre[t - off] : 0;
        __syncthreads();
        if (t < 128) pre[t] += add;
        __syncthreads();
    }
    int excl = (blockIdx.x == 0) ? 0 : pre[blockIdx.x - 1];
    int i = blockIdx.x * SB + t;
    if (i < N_NODES) {
        int s = start[i] + excl;
        start[i] = s;
        cursor[i] = s;
    }
}

// pack {src, m-bits} into one 8B entry.
__global__ void fill_kernel(const int* __restrict__ src, const int* __restrict__ dst,
                            const float* __restrict__ M, int* __restrict__ cursor,
                            i32x2* __restrict__ csr_sm) {
    int e = blockIdx.x * 256 + threadIdx.x;
    if (e < N_EDGES) {
        int d = dst[e];
        int pos = atomicAdd(&cursor[d], 1);
        i32x2 v;
        v.x = src[e];
        v.y = __float_as_int(M[e]);
        __builtin_nontemporal_store(v, csr_sm + pos);
    }
}

// One wave per node, ALL 8 heads per iteration. Lane l: head = l>>3,
// features (l&7)*8..+8. h rows are int8 (512B/row -> half the gather bytes
// of bf16); per-(src,head) dequant scale rides along with a_self in one
// float2 (same 8B gather, same line footprint as before). Depth-2 pipeline
// retained (VALU-harmless, VGPR 32).
__global__ __launch_bounds__(256) void agg_kernel(const signed char* __restrict__ hb,
                                                  const float2* __restrict__ asc,
                                                  const float* __restrict__ a_neigh,
                                                  const int* __restrict__ start,
                                                  const int* __restrict__ deg,
                                                  const i32x2* __restrict__ csr_sm,
                                                  float* __restrict__ out) {
    int n = blockIdx.x * 4 + (threadIdx.x >> 6);
    if (n >= N_NODES) return;
    const int lane = threadIdx.x & 63;
    const int head = lane >> 3;

    const int d = deg[n];
    const float an = a_neigh[(n << 3) + head];
    const signed char* hbl = hb + (lane << 3);
    const float2* aslc = asc + head;
    const i32x2* cp = csr_sm + start[n];

    float facc[8];
#pragma unroll
    for (int k = 0; k < 8; k++) facc[k] = 0.f;
    float den = 0.f;

    i32x2 zero = 0;
    i32x2 smA = (d > 0) ? cp[0] : zero;
    i32x2 smB = (d > 1) ? cp[1] : smA;
    i32x2 smC = (d > 2) ? cp[2] : smB;
    i32x2 smD = (d > 3) ? cp[3] : smC;
    float2 aA = aslc[(size_t)smA.x << 3];
    schar8 hvA = *(const schar8*)(hbl + ((size_t)smA.x << 9));
    float2 aB = aslc[(size_t)smB.x << 3];
    schar8 hvB = *(const schar8*)(hbl + ((size_t)smB.x << 9));

    int j = 0;
    for (; j + 2 <= d; j += 2) {
        // issue: csr 4 ahead, gathers 2 ahead
        i32x2 smE = (j + 4 < d) ? cp[j + 4] : smD;
        i32x2 smF = (j + 5 < d) ? cp[j + 5] : smE;
        float2 aC = aslc[(size_t)smC.x << 3];
        schar8 hvC = *(const schar8*)(hbl + ((size_t)smC.x << 9));
        float2 aD = aslc[(size_t)smD.x << 3];
        schar8 hvD = *(const schar8*)(hbl + ((size_t)smD.x << 9));

        // compute edge j (slot A)
        float eA = aA.x + an;
        eA = (eA > 0.f) ? eA : SLOPE * eA;
        const float wA = __expf(eA * __int_as_float(smA.y));
        const float wsA = wA * aA.y;
#pragma unroll
        for (int k = 0; k < 8; k++) facc[k] = fmaf(wsA, (float)hvA[k], facc[k]);
        den += wA;

        // compute edge j+1 (slot B)
        float eB = aB.x + an;
        eB = (eB > 0.f) ? eB : SLOPE * eB;
        const float wB = __expf(eB * __int_as_float(smB.y));
        const float wsB = wB * aB.y;
#pragma unroll
        for (int k = 0; k < 8; k++) facc[k] = fmaf(wsB, (float)hvB[k], facc[k]);
        den += wB;

        // rotate pipeline
        smA = smC; aA = aC; hvA = hvC;
        smB = smD; aB = aD; hvB = hvD;
        smC = smE; smD = smF;
    }
    if (j < d) {   // odd tail: one edge left in slot A
        float eA = aA.x + an;
        eA = (eA > 0.f) ? eA : SLOPE * eA;
        const float wA = __expf(eA * __int_as_float(smA.y));
        const float wsA = wA * aA.y;
#pragma unroll
        for (int k = 0; k < 8; k++) facc[k] = fmaf(wsA, (float)hvA[k], facc[k]);
        den += wA;
    }

    const float inv = 1.f / (den + 1e-16f);
    float r[8];
#pragma unroll
    for (int k = 0; k < 8; k++) {
        float v = facc[k] * inv;
        r[k] = (v > 0.f) ? v : expm1f(v);   // elu
    }
    float* ob = &out[((size_t)n << 9) + (lane << 3)];
    *(float4*)(ob)     = make_float4(r[0], r[1], r[2], r[3]);
    *(float4*)(ob + 4) = make_float4(r[4], r[5], r[6], r[7]);
}

extern "C" void kernel_launch(void* const* d_in, const int* in_sizes, int n_in,
                              void* d_out, int out_size, void* d_ws, size_t ws_size,
                              hipStream_t stream) {
    const float* x   = (const float*)d_in[0];
    const int*   src = (const int*)d_in[1];
    const int*   dst = (const int*)d_in[2];
    const float* M   = (const float*)d_in[3];
    const float* W   = (const float*)d_in[4];
    const float* a   = (const float*)d_in[5];
    float* out = (float*)d_out;

    char* p = (char*)d_ws;
    auto alloc = [&](size_t bytes) {
        char* r = p;
        p += (bytes + 255) & ~(size_t)255;
        return r;
    };
    signed char* hb = (signed char*)alloc((size_t)N_NODES * N_HEADS * OUT_F);
    float2* asc     = (float2*)alloc(sizeof(float2) * N_NODES * N_HEADS);
    float*  a_neigh = (float*)alloc(sizeof(float) * N_NODES * N_HEADS);
    int*    deg     = (int*)alloc(sizeof(int) * N_NODES);
    int*    start   = (int*)alloc(sizeof(int) * N_NODES);
    int*    cursor  = (int*)alloc(sizeof(int) * N_NODES);
    int*    bsum    = (int*)alloc(sizeof(int) * 256);
    i32x2*  csr_sm  = (i32x2*)alloc(sizeof(i32x2) * N_EDGES);
    __bf16* Wt      = (__bf16*)alloc(sizeof(__bf16) * N_HEADS * IN_F * OUT_F);

    // --- prep: zero deg, then fused hist + cast_w ---
    hipMemsetAsync(deg, 0, sizeof(int) * N_NODES, stream);
    prep_kernel<<<PREP_BLOCKS, 256, 0, stream>>>(W, dst, Wt, deg);

    // --- CSR scan + fill ---
    scanA<<<NSB, SB, 0, stream>>>(deg, start, bsum);
    scanC<<<NSB, SB, 0, stream>>>(start, bsum, cursor);
    fill_kernel<<<(N_EDGES + 255) / 256, 256, 0, stream>>>(src, dst, M, cursor, csr_sm);

    // --- fused cast + feature transform + attn dots + int8 quant ---
    mfma_gemm_kernel<<<1563, 256, 0, stream>>>(x, Wt, a, hb, asc, a_neigh);

    // --- fused attention + aggregation + elu (all heads per wave) ---
    agg_kernel<<<(N_NODES + 3) / 4, 256, 0, stream>>>(hb, asc, a_neigh,
                                                      start, deg, csr_sm, out);
}

// Round 4
// 401.302 us; speedup vs baseline: 1.1153x; 1.0083x over previous
//
#include <hip/hip_runtime.h>
#include <math.h>

#define N_NODES 50000
#define N_EDGES 800000
#define IN_F 256
#define OUT_F 64
#define N_HEADS 8
#define SLOPE 0.2f

typedef __attribute__((ext_vector_type(8))) __bf16 bf16x8;
typedef __attribute__((ext_vector_type(4))) __bf16 bf16x4;
typedef __attribute__((ext_vector_type(4))) float floatx4;
typedef __attribute__((ext_vector_type(4))) float f32x4;
typedef __attribute__((ext_vector_type(2))) int i32x2;
typedef __attribute__((ext_vector_type(2))) unsigned int u32x2;
typedef __attribute__((ext_vector_type(8))) char schar8;

#define HIST_BLOCKS   3125    // 800000/256
#define CAST_W_BLOCKS 512     // 8*256*64/256
#define PREP_BLOCKS   (HIST_BLOCKS + CAST_W_BLOCKS)

// Prep: dst-degree histogram + cast/transpose W->bf16.
__global__ __launch_bounds__(256) void prep_kernel(const float* __restrict__ W,
                                                   const int* __restrict__ dst,
                                                   __bf16* __restrict__ Wt,
                                                   int* __restrict__ deg) {
    const int b = blockIdx.x;
    const int t = threadIdx.x;
    if (b < HIST_BLOCKS) {
        int e = b * 256 + t;                  // exact: 800000
        atomicAdd(&deg[dst[e]], 1);
    } else {
        int i = (b - HIST_BLOCKS) * 256 + t;  // exact: 131072 elems
        int n = i & (OUT_F - 1);
        int k = (i >> 6) & (IN_F - 1);
        int h = i >> 14;
        Wt[((size_t)h * OUT_F + n) * IN_F + k] = (__bf16)W[i];
    }
}

// Fused GEMM + attention dots + uint8 (biased +128) quantization of h.
// h stored uint8 with per-(node,head) symmetric scale (rowmax/127):
// value = (u - 128) * scale. Biased-unsigned lets agg use the 1-op
// v_cvt_f32_ubyteN converts; the -128 term is corrected via one running sum.
// Attention dots stay fp32 from the MFMA accumulator.
#define XPAD 264   // 256 + 8 bf16 pad: 528B row stride -> 2-way banks (free)
__global__ __launch_bounds__(256) void mfma_gemm_kernel(const float* __restrict__ x,
                                                        const __bf16* __restrict__ Wt,
                                                        const float* __restrict__ a,
                                                        unsigned char* __restrict__ hb,
                                                        float2* __restrict__ asc,
                                                        float* __restrict__ a_neigh) {
    __shared__ __bf16 xs[32][XPAD];
    const int warp = threadIdx.x >> 6;
    const int tile = blockIdx.x;              // 0..1562
    const int n0 = tile * 32;
    const int lane = threadIdx.x & 63;
    const int l15 = lane & 15;
    const int quad = lane >> 4;
    const int h0 = warp * 2;

    // ---- stage x tile (32 rows x 256 k) with inline fp32->bf16 cast ----
#pragma unroll
    for (int i = 0; i < 8; i++) {
        int c4 = i * 256 + threadIdx.x;       // float4 chunk id 0..2047
        int row = c4 >> 6;                    // 64 chunks per row
        int col = (c4 & 63) * 4;
        int node = n0 + row;
        node = (node < N_NODES) ? node : (N_NODES - 1);
        f32x4 v = __builtin_nontemporal_load((const f32x4*)x + (size_t)node * 64 + (c4 & 63));
        bf16x4 o;
        o[0] = (__bf16)v[0]; o[1] = (__bf16)v[1]; o[2] = (__bf16)v[2]; o[3] = (__bf16)v[3];
        *(bf16x4*)&xs[row][col] = o;
    }
    __syncthreads();

    floatx4 acc[2][2][4];   // [head][rowblock][col]
#pragma unroll
    for (int hh = 0; hh < 2; hh++)
#pragma unroll
        for (int i = 0; i < 2; i++)
#pragma unroll
            for (int c = 0; c < 4; c++) acc[hh][i][c] = floatx4{0.f, 0.f, 0.f, 0.f};

    const __bf16* wb0 = Wt + ((size_t)h0 * OUT_F + l15) * IN_F + quad * 8;
    const __bf16* wb1 = wb0 + (size_t)OUT_F * IN_F;

#pragma unroll
    for (int k0 = 0; k0 < IN_F; k0 += 32) {
        bf16x8 a0 = *(const bf16x8*)&xs[l15][k0 + quad * 8];
        bf16x8 a1 = *(const bf16x8*)&xs[l15 + 16][k0 + quad * 8];
#pragma unroll
        for (int c = 0; c < 4; c++) {
            bf16x8 b0 = *(const bf16x8*)(wb0 + (size_t)c * 16 * IN_F + k0);
            acc[0][0][c] = __builtin_amdgcn_mfma_f32_16x16x32_bf16(a0, b0, acc[0][0][c], 0, 0, 0);
            acc[0][1][c] = __builtin_amdgcn_mfma_f32_16x16x32_bf16(a1, b0, acc[0][1][c], 0, 0, 0);
            bf16x8 b1 = *(const bf16x8*)(wb1 + (size_t)c * 16 * IN_F + k0);
            acc[1][0][c] = __builtin_amdgcn_mfma_f32_16x16x32_bf16(a0, b1, acc[1][0][c], 0, 0, 0);
            acc[1][1][c] = __builtin_amdgcn_mfma_f32_16x16x32_bf16(a1, b1, acc[1][1][c], 0, 0, 0);
        }
    }

    __syncthreads();   // all waves done reading xs; reuse as uint8 transpose buf
    char* myc = (char*)xs + warp * (32 * OUT_F);   // 2KB per warp, disjoint

#pragma unroll
    for (int hh = 0; hh < 2; hh++) {
        const int head = h0 + hh;
        float av0[4], av1[4];
#pragma unroll
        for (int c = 0; c < 4; c++) {
            av0[c] = a[head * 2 * OUT_F + c * 16 + l15];
            av1[c] = a[head * 2 * OUT_F + OUT_F + c * 16 + l15];
        }
#pragma unroll
        for (int i = 0; i < 2; i++) {
#pragma unroll
            for (int reg = 0; reg < 4; reg++) {
                float ps = 0.f, pn = 0.f, rm = 0.f;
#pragma unroll
                for (int c = 0; c < 4; c++) {
                    float v = acc[hh][i][c][reg];
                    ps = fmaf(v, av0[c], ps);
                    pn = fmaf(v, av1[c], pn);
                    rm = fmaxf(rm, fabsf(v));
                }
#pragma unroll
                for (int off = 1; off < 16; off <<= 1) {
                    ps += __shfl_xor(ps, off, 64);
                    pn += __shfl_xor(pn, off, 64);
                    rm = fmaxf(rm, __shfl_xor(rm, off, 64));
                }
                const float inv = (rm > 0.f) ? 127.f / rm : 0.f;
                const int rowoff = (i * 16 + quad * 4 + reg) * OUT_F;
#pragma unroll
                for (int c = 0; c < 4; c++) {
                    float q = rintf(acc[hh][i][c][reg] * inv);
                    q = fminf(fmaxf(q, -127.f), 127.f);
                    myc[rowoff + c * 16 + l15] = (char)((int)q + 128);   // biased uint8
                }
                int node = n0 + i * 16 + quad * 4 + reg;
                if (l15 == 0 && node < N_NODES) {
                    asc[node * N_HEADS + head] = make_float2(ps, rm * (1.f / 127.f));
                    a_neigh[node * N_HEADS + head] = pn;
                }
            }
        }
        // coalesced uint8 h store (wave-private region, in-wave LDS ordering)
#pragma unroll
        for (int pass = 0; pass < 4; pass++) {
            int row = pass * 8 + (lane >> 3);
            int node = n0 + row;
            schar8 v = *(const schar8*)&myc[row * OUT_F + (lane & 7) * 8];
            if (node < N_NODES)
                *(schar8*)(hb + ((size_t)(node * N_HEADS + head) << 6) + (lane & 7) * 8) = v;
        }
    }
}

#define SB 512
#define NSB 98   // ceil(50000/512)
__global__ void scanA(const int* __restrict__ deg, int* __restrict__ start,
                      int* __restrict__ bsum) {
    __shared__ int tmp[SB];
    int t = threadIdx.x, i = blockIdx.x * SB + t;
    int v = (i < N_NODES) ? deg[i] : 0;
    tmp[t] = v;
    for (int off = 1; off < SB; off <<= 1) {
        __syncthreads();
        int add = (t >= off) ? tmp[t - off] : 0;
        __syncthreads();
        tmp[t] += add;
    }
    if (i < N_NODES) start[i] = tmp[t] - v;
    if (t == SB - 1) bsum[blockIdx.x] = tmp[SB - 1];
}

__global__ void scanC(int* __restrict__ start, const int* __restrict__ bsum,
                      int* __restrict__ cursor) {
    __shared__ int pre[128];
    int t = threadIdx.x;
    if (t < 128) pre[t] = (t < NSB) ? bsum[t] : 0;
    __syncthreads();
    for (int off = 1; off < 128; off <<= 1) {
        int add = (t < 128 && t >= off) ? pre[t - off] : 0;
        __syncthreads();
        if (t < 128) pre[t] += add;
        __syncthreads();
    }
    int excl = (blockIdx.x == 0) ? 0 : pre[blockIdx.x - 1];
    int i = blockIdx.x * SB + t;
    if (i < N_NODES) {
        int s = start[i] + excl;
        start[i] = s;
        cursor[i] = s;
    }
}

// pack {src, M*log2(e) bits} into one 8B entry. Premultiplying by log2(e)
// lets agg use exp2 (native v_exp_f32) with no extra multiply.
__global__ void fill_kernel(const int* __restrict__ src, const int* __restrict__ dst,
                            const float* __restrict__ M, int* __restrict__ cursor,
                            i32x2* __restrict__ csr_sm) {
    int e = blockIdx.x * 256 + threadIdx.x;
    if (e < N_EDGES) {
        int d = dst[e];
        int pos = atomicAdd(&cursor[d], 1);
        i32x2 v;
        v.x = src[e];
        v.y = __float_as_int(M[e] * 1.44269504f);
        __builtin_nontemporal_store(v, csr_sm + pos);
    }
}

// One wave per node, ALL 8 heads per iteration. Lane l: head = l>>3,
// features (l&7)*8..+8. VALU-lean edge loop (~36 instrs/edge):
//  - uint8 h rows -> v_cvt_f32_ubyteN (1 op/elem, vs 2 for sext int8);
//    -128 bias corrected once via sacc = sum(w*scale).
//  - mov-free ping-pong unroll-2 (slots P/Q are loop-carried registers,
//    no rotation movs); 1-ahead issue (R0 vs R2: latency fully TLP-hidden).
//  - min-clamped prefetch index (no cmp+cndmask chains); d==0 early-out.
//  - exp2f on premultiplied logits.
__global__ __launch_bounds__(256) void agg_kernel(const unsigned char* __restrict__ hb,
                                                  const float2* __restrict__ asc,
                                                  const float* __restrict__ a_neigh,
                                                  const int* __restrict__ start,
                                                  const int* __restrict__ deg,
                                                  const i32x2* __restrict__ csr_sm,
                                                  float* __restrict__ out) {
    int n = blockIdx.x * 4 + (threadIdx.x >> 6);
    if (n >= N_NODES) return;
    const int lane = threadIdx.x & 63;
    const int head = lane >> 3;

    const int d = deg[n];
    float* ob = &out[((size_t)n << 9) + (lane << 3)];
    if (d == 0) {   // isolated node: h_prime = 0 -> elu(0) = 0
        f32x4 z = {0.f, 0.f, 0.f, 0.f};
        *(f32x4*)(ob) = z;
        *(f32x4*)(ob + 4) = z;
        return;
    }
    const int dm1 = d - 1;
    const float an = a_neigh[(n << 3) + head];
    const unsigned char* hbl = hb + (lane << 3);
    const float2* aslc = asc + head;
    const i32x2* cp = csr_sm + start[n];

    float facc[8];
#pragma unroll
    for (int k = 0; k < 8; k++) facc[k] = 0.f;
    float den = 0.f, sacc = 0.f;

    auto edge = [&](const i32x2& sm, const float2& a2, const u32x2& hv) {
        float e_ = a2.x + an;
        e_ = (e_ > 0.f) ? e_ : SLOPE * e_;
        const float w_ = exp2f(e_ * __int_as_float(sm.y));
        const float ws = w_ * a2.y;
        den += w_;
        sacc += ws;
        facc[0] = fmaf(ws, (float)(hv.x & 0xffu), facc[0]);
        facc[1] = fmaf(ws, (float)((hv.x >> 8) & 0xffu), facc[1]);
        facc[2] = fmaf(ws, (float)((hv.x >> 16) & 0xffu), facc[2]);
        facc[3] = fmaf(ws, (float)(hv.x >> 24), facc[3]);
        facc[4] = fmaf(ws, (float)(hv.y & 0xffu), facc[4]);
        facc[5] = fmaf(ws, (float)((hv.y >> 8) & 0xffu), facc[5]);
        facc[6] = fmaf(ws, (float)((hv.y >> 16) & 0xffu), facc[6]);
        facc[7] = fmaf(ws, (float)(hv.y >> 24), facc[7]);
    };

    // prologue: slot P = edge 0
    i32x2 smP = cp[0];
    float2 aP = aslc[(size_t)smP.x << 3];
    u32x2 hvP = *(const u32x2*)(hbl + ((size_t)smP.x << 9));

    int j = 0;
    for (; j + 2 <= d; j += 2) {
        // slot Q = edge j+1 (always valid: j+1 <= d-1)
        i32x2 smQ = cp[j + 1];
        float2 aQ = aslc[(size_t)smQ.x << 3];
        u32x2 hvQ = *(const u32x2*)(hbl + ((size_t)smQ.x << 9));
        edge(smP, aP, hvP);
        // slot P = edge j+2 (clamped: redundant reload of dm1 on last iter)
        int i2 = (j + 2 < d) ? (j + 2) : dm1;
        smP = cp[i2];
        aP = aslc[(size_t)smP.x << 3];
        hvP = *(const u32x2*)(hbl + ((size_t)smP.x << 9));
        edge(smQ, aQ, hvQ);
    }
    if (j < d) edge(smP, aP, hvP);

    const float inv = 1.f / (den + 1e-16f);
    float r[8];
#pragma unroll
    for (int k = 0; k < 8; k++) {
        float v = fmaf(-128.f, sacc, facc[k]) * inv;   // undo +128 bias
        r[k] = (v > 0.f) ? v : expm1f(v);   // elu
    }
    *(float4*)(ob)     = make_float4(r[0], r[1], r[2], r[3]);
    *(float4*)(ob + 4) = make_float4(r[4], r[5], r[6], r[7]);
}

extern "C" void kernel_launch(void* const* d_in, const int* in_sizes, int n_in,
                              void* d_out, int out_size, void* d_ws, size_t ws_size,
                              hipStream_t stream) {
    const float* x   = (const float*)d_in[0];
    const int*   src = (const int*)d_in[1];
    const int*   dst = (const int*)d_in[2];
    const float* M   = (const float*)d_in[3];
    const float* W   = (const float*)d_in[4];
    const float* a   = (const float*)d_in[5];
    float* out = (float*)d_out;

    char* p = (char*)d_ws;
    auto alloc = [&](size_t bytes) {
        char* r = p;
        p += (bytes + 255) & ~(size_t)255;
        return r;
    };
    unsigned char* hb = (unsigned char*)alloc((size_t)N_NODES * N_HEADS * OUT_F);
    float2* asc     = (float2*)alloc(sizeof(float2) * N_NODES * N_HEADS);
    float*  a_neigh = (float*)alloc(sizeof(float) * N_NODES * N_HEADS);
    int*    deg     = (int*)alloc(sizeof(int) * N_NODES);
    int*    start   = (int*)alloc(sizeof(int) * N_NODES);
    int*    cursor  = (int*)alloc(sizeof(int) * N_NODES);
    int*    bsum    = (int*)alloc(sizeof(int) * 256);
    i32x2*  csr_sm  = (i32x2*)alloc(sizeof(i32x2) * N_EDGES);
    __bf16* Wt      = (__bf16*)alloc(sizeof(__bf16) * N_HEADS * IN_F * OUT_F);

    // --- prep: zero deg, then fused hist + cast_w ---
    hipMemsetAsync(deg, 0, sizeof(int) * N_NODES, stream);
    prep_kernel<<<PREP_BLOCKS, 256, 0, stream>>>(W, dst, Wt, deg);

    // --- CSR scan + fill ---
    scanA<<<NSB, SB, 0, stream>>>(deg, start, bsum);
    scanC<<<NSB, SB, 0, stream>>>(start, bsum, cursor);
    fill_kernel<<<(N_EDGES + 255) / 256, 256, 0, stream>>>(src, dst, M, cursor, csr_sm);

    // --- fused cast + feature transform + attn dots + uint8 quant ---
    mfma_gemm_kernel<<<1563, 256, 0, stream>>>(x, Wt, a, hb, asc, a_neigh);

    // --- fused attention + aggregation + elu (all heads per wave) ---
    agg_kernel<<<(N_NODES + 3) / 4, 256, 0, stream>>>(hb, asc, a_neigh,
                                                      start, deg, csr_sm, out);
}